// Round 3
// baseline (360.944 us; speedup 1.0000x reference)
//
#include <hip/hip_runtime.h>
#include <hip/hip_fp16.h>

#define N_NODES 100000
#define N_EDGES 1600000
#define NPB 128                                   // nodes per dst-bucket
#define NBK ((N_NODES + NPB - 1) / NPB)           // 782 buckets
#define FBLK 256                                  // fill blocks (1 per CU)
#define EPB ((N_EDGES + FBLK - 1) / FBLK)         // 6250 edges per fill block
#define CAP 4096                                  // LDS capacity per bucket (mean 2046, sigma ~45)
#define NROW 100032                               // padded row count per column plane
#define SENT 100000                               // sentinel row (zeroed in every plane)

typedef _Float16 h8 __attribute__((ext_vector_type(8)));
typedef float f4v __attribute__((ext_vector_type(4)));

// ---------------- pass 1: per-block bucket histograms ----------------

__global__ void __launch_bounds__(256) hist_kernel(const int* __restrict__ dst, int* __restrict__ H) {
    __shared__ int h[NBK];
    for (int i = threadIdx.x; i < NBK; i += 256) h[i] = 0;
    __syncthreads();
    const int e0 = blockIdx.x * EPB;
    const int e1 = min(e0 + EPB, N_EDGES);
    for (int e = e0 + threadIdx.x; e < e1; e += 256) atomicAdd(&h[dst[e] >> 7], 1);
    __syncthreads();
    for (int i = threadIdx.x; i < NBK; i += 256) H[blockIdx.x * NBK + i] = h[i];
}

// ---------------- pass 2a: per-bucket column scan over the FBLK blocks ----------------

__global__ void __launch_bounds__(256) colscan_kernel(int* __restrict__ H, int* __restrict__ btot) {
    const int t = blockIdx.x * 256 + threadIdx.x;
    if (t >= NBK) return;
    int run = 0;
    for (int k = 0; k < FBLK; ++k) {
        int idx = k * NBK + t;
        int h = H[idx];
        H[idx] = run;
        run += h;
    }
    btot[t] = run;
}

// ---------------- pass 2b: scan bucket totals -> bucket bases + bptr ----------------

__global__ void __launch_bounds__(1024) bucketscan_kernel(const int* __restrict__ btot,
                                                          int* __restrict__ bbase, int* __restrict__ bptr) {
    __shared__ int sh[1024];
    const int t = threadIdx.x;
    int v = (t < NBK) ? btot[t] : 0;
    sh[t] = v;
    __syncthreads();
    for (int off = 1; off < 1024; off <<= 1) {
        int u = (t >= off) ? sh[t - off] : 0;
        __syncthreads();
        sh[t] += u;
        __syncthreads();
    }
    if (t < NBK) { int e = sh[t] - v; bbase[t] = e; bptr[t] = e; }
    if (t == 0) bptr[NBK] = N_EDGES;
}

// ---------------- pass 3: bin edges by bucket (LDS cursors) ----------------

__global__ void __launch_bounds__(256) binfill_kernel(const int* __restrict__ src, const int* __restrict__ dst,
                                                      const int* __restrict__ H, const int* __restrict__ bbase,
                                                      int* __restrict__ tmp) {
    __shared__ int cur[NBK];
    const int k = blockIdx.x;
    for (int i = threadIdx.x; i < NBK; i += 256) cur[i] = H[k * NBK + i] + bbase[i];
    __syncthreads();
    const int e0 = k * EPB;
    const int e1 = min(e0 + EPB, N_EDGES);
    for (int e = e0 + threadIdx.x; e < e1; e += 256) {
        int s = src[e];
        int d = dst[e];
        int pos = atomicAdd(&cur[d >> 7], 1);
        tmp[pos] = s | ((d & (NPB - 1)) << 20);
    }
}

// ---------------- pass 4: per-bucket count/scan/rowptr/dis + LDS sort -> esrc ----------------

__global__ void __launch_bounds__(256) bucketfin_kernel(const int* __restrict__ tmp, const int* __restrict__ bptr,
                                                        int* __restrict__ esrc, int* __restrict__ rowptr,
                                                        float* __restrict__ dis, int n) {
    __shared__ int buf[CAP];
    __shared__ int cnt[NPB];
    __shared__ int sc[NPB];
    __shared__ int rp[NPB];
    __shared__ int fillc[NPB];
    const int b = blockIdx.x;
    const int d0 = b * NPB;
    const int nd = min(NPB, n - d0);
    const int base = bptr[b], end = bptr[b + 1];
    const int count = end - base;
    const int tid = threadIdx.x;

    for (int i = tid; i < NPB; i += 256) { cnt[i] = 0; fillc[i] = 0; }
    __syncthreads();
    for (int e = base + tid; e < end; e += 256) atomicAdd(&cnt[tmp[e] >> 20], 1);
    __syncthreads();

    if (tid < NPB) sc[tid] = cnt[tid];
    __syncthreads();
    for (int off = 1; off < NPB; off <<= 1) {
        int v = (tid < NPB && tid >= off) ? sc[tid - off] : 0;
        __syncthreads();
        if (tid < NPB) sc[tid] += v;
        __syncthreads();
    }
    if (tid < NPB) {
        int excl = sc[tid] - cnt[tid];
        rp[tid] = excl;
        if (tid < nd) {
            rowptr[d0 + tid] = base + excl;
            dis[d0 + tid] = rsqrtf((float)cnt[tid] + 1.0f);
        }
    }
    if (b == NBK - 1 && tid == 0) rowptr[n] = N_EDGES;
    __syncthreads();

    if (count <= CAP) {
        for (int t = base + tid; t < end; t += 256) {
            int w = tmp[t];
            int ld = w >> 20;
            int pos = rp[ld] + atomicAdd(&fillc[ld], 1);
            buf[pos] = w & 0xFFFFF;
        }
        __syncthreads();
        for (int t = tid; t < count; t += 256) esrc[base + t] = buf[t];
    } else {
        for (int t = base + tid; t < end; t += 256) {
            int w = tmp[t];
            int ld = w >> 20;
            int pos = rp[ld] + atomicAdd(&fillc[ld], 1);
            esrc[base + pos] = w & 0xFFFFF;
        }
    }
}

// ---------------- weight transposes -> fp16 W^T, plus zero the sentinel row in all 4 planes ----------------

__global__ void transpose_all_kernel(const float* __restrict__ W0, const float* __restrict__ W1,
                                     const float* __restrict__ W2, __half* __restrict__ wt0,
                                     __half* __restrict__ wt1, __half* __restrict__ wt2,
                                     __half* __restrict__ ys) {
    int i = blockIdx.x * blockDim.x + threadIdx.x;
    if (i < 8192)       { int k = i / 64, c = i % 64;                 wt0[c * 128 + k] = __float2half(W0[i]); }
    else if (i < 12288) { int j = i - 8192;  int k = j / 64, c = j % 64; wt1[c * 64 + k] = __float2half(W1[j]); }
    else if (i < 14336) { int j = i - 12288; int k = j / 32, c = j % 32; wt2[c * 64 + k] = __float2half(W2[j]); }
    else if (i < 14368) {                                              // 4 planes x 16 halves (8 ints each)
        int j = i - 14336;
        int cb = j >> 3, w = j & 7;
        ((int*)ys)[((long)cb * NROW + SENT) * 8 + w] = 0;
    }
}

// ---------------- MFMA GEMM: ys planes = fp16(dis[row] * (x[n,DIN] @ W)) ----------------
// Output layout: column-blocked planes, element (r,c) -> ys[((c>>4)*NROW + r)*16 + (c&15)].

template <typename TIN, int DIN, int DOUT>
__global__ void __launch_bounds__(256) gemm_kernel(const TIN* __restrict__ x,
                                                   const __half* __restrict__ wt16,
                                                   const float* __restrict__ dis,
                                                   __half* __restrict__ ys, int n) {
    constexpr int WS = DIN + 8;          // half-element stride (16B-aligned, 2-way banks = free)
    constexpr int NT = DOUT / 16;
    constexpr int KC = DIN / 32;

    __shared__ _Float16 xls[64 * WS];
    __shared__ _Float16 wls[DOUT * WS];

    const int tid  = threadIdx.x;
    const int row0 = blockIdx.x * 64;

    for (int i = tid; i < DOUT * DIN / 8; i += 256) {
        int c = (i * 8) / DIN, k = (i * 8) % DIN;
        *(int4*)&wls[c * WS + k] = *(const int4*)&wt16[c * DIN + k];
    }
    if constexpr (sizeof(TIN) == 4) {            // fp32 -> fp16 convert
        for (int i = tid; i < 64 * DIN / 4; i += 256) {
            int r = (i * 4) / DIN, k = (i * 4) % DIN;
            float4 v = make_float4(0.f, 0.f, 0.f, 0.f);
            if (row0 + r < n) v = *(const float4*)&x[(long)(row0 + r) * DIN + k];
            _Float16 h[4] = {(_Float16)v.x, (_Float16)v.y, (_Float16)v.z, (_Float16)v.w};
            *(int2*)&xls[r * WS + k] = *(int2*)h;
        }
    } else {                                      // fp16 direct 16B copy
        for (int i = tid; i < 64 * DIN / 8; i += 256) {
            int r = (i * 8) / DIN, k = (i * 8) % DIN;
            int4 v = make_int4(0, 0, 0, 0);
            if (row0 + r < n) v = *(const int4*)&x[(long)(row0 + r) * DIN + k];
            *(int4*)&xls[r * WS + k] = v;
        }
    }
    __syncthreads();

    const int wave = tid >> 6;
    const int lane = tid & 63;
    const int m16  = lane & 15;
    const int quad = lane >> 4;

    f4v acc[NT];
#pragma unroll
    for (int t = 0; t < NT; ++t) acc[t] = (f4v){0.f, 0.f, 0.f, 0.f};

    const int arow = wave * 16 + m16;
#pragma unroll
    for (int kc = 0; kc < KC; ++kc) {
        h8 a = *(const h8*)&xls[arow * WS + kc * 32 + quad * 8];
#pragma unroll
        for (int t = 0; t < NT; ++t) {
            h8 b = *(const h8*)&wls[(t * 16 + m16) * WS + kc * 32 + quad * 8];
            acc[t] = __builtin_amdgcn_mfma_f32_16x16x32_f16(a, b, acc[t], 0, 0, 0);
        }
    }

    // epilogue: fold dis, repack via LDS (reuse xls), column-blocked int4 stores
    float dsv[4];
    int   lrow[4];
#pragma unroll
    for (int reg = 0; reg < 4; ++reg) {
        lrow[reg] = wave * 16 + quad * 4 + reg;
        int grow  = row0 + lrow[reg];
        dsv[reg]  = (grow < n) ? dis[grow] : 0.f;
    }
    __syncthreads();
    _Float16* stage = xls;
#pragma unroll
    for (int t = 0; t < NT; ++t) {
#pragma unroll
        for (int reg = 0; reg < 4; ++reg)
            stage[lrow[reg] * DOUT + t * 16 + m16] = (_Float16)(acc[t][reg] * dsv[reg]);
    }
    __syncthreads();
    for (int i = tid; i < 64 * DOUT / 8; i += 256) {
        int off = i * 8;
        int r = off / DOUT;
        int c = off % DOUT;                       // multiple of 8 -> stays inside one 16-col plane
        if (row0 + r < n)
            *(int4*)&ys[((long)(c >> 4) * NROW + row0 + r) * 16 + (c & 15)] = *(int4*)&stage[off];
    }
}

// ---------------- gather helpers: accumulate 8 halves (int4) into 8 floats ----------------

__device__ __forceinline__ void acc8(int4 w, float* a) {
    __half2* h = (__half2*)&w;
    float2 f0 = __half22float2(h[0]);
    float2 f1 = __half22float2(h[1]);
    float2 f2 = __half22float2(h[2]);
    float2 f3 = __half22float2(h[3]);
    a[0] += f0.x; a[1] += f0.y; a[2] += f1.x; a[3] += f1.y;
    a[4] += f2.x; a[5] += f2.y; a[6] += f3.x; a[7] += f3.y;
}

// ---------------- gather DOUT=64: column-phased, 4 passes x 16-col plane (3.2 MB, L2-resident) ----------------
// 128 nodes/block, 2 lanes/node x 16B. All 782 blocks co-resident -> passes phase-aligned chip-wide.
// out[d] = fp16( relu( dis[d] * (ys[d] + sum_edges ys[s]) + b ) ), act written row-major.

__global__ void __launch_bounds__(256) gather2h_kernel(const int* __restrict__ rowptr, const int* __restrict__ esrc,
                                                       const __half* __restrict__ ys, const float* __restrict__ dis,
                                                       const float* __restrict__ b, __half* __restrict__ out, int n) {
    const int node = blockIdx.x * 128 + (threadIdx.x >> 1);
    const int sel = (threadIdx.x & 1) * 8;        // 8 halves within the 16-col plane
    if (node >= n) return;

    const float di   = dis[node];
    const int   kbeg = rowptr[node];
    const int   end  = rowptr[node + 1];

    for (int cb = 0; cb < 4; ++cb) {
        const __half* yb = ys + (long)cb * NROW * 16;
        float a[8];
        {
            int4 sw = *(const int4*)&yb[(long)node * 16 + sel];   // self term (pre-scaled)
            __half2* h = (__half2*)&sw;
            float2 f0 = __half22float2(h[0]);
            float2 f1 = __half22float2(h[1]);
            float2 f2 = __half22float2(h[2]);
            float2 f3 = __half22float2(h[3]);
            a[0] = f0.x; a[1] = f0.y; a[2] = f1.x; a[3] = f1.y;
            a[4] = f2.x; a[5] = f2.y; a[6] = f3.x; a[7] = f3.y;
        }

        for (int k = kbeg; k < end; k += 8) {
            int u0 = (k + 0 < end) ? esrc[k + 0] : SENT;
            int u1 = (k + 1 < end) ? esrc[k + 1] : SENT;
            int u2 = (k + 2 < end) ? esrc[k + 2] : SENT;
            int u3 = (k + 3 < end) ? esrc[k + 3] : SENT;
            int u4 = (k + 4 < end) ? esrc[k + 4] : SENT;
            int u5 = (k + 5 < end) ? esrc[k + 5] : SENT;
            int u6 = (k + 6 < end) ? esrc[k + 6] : SENT;
            int u7 = (k + 7 < end) ? esrc[k + 7] : SENT;
            int4 w0 = *(const int4*)&yb[(long)u0 * 16 + sel];
            int4 w1 = *(const int4*)&yb[(long)u1 * 16 + sel];
            int4 w2 = *(const int4*)&yb[(long)u2 * 16 + sel];
            int4 w3 = *(const int4*)&yb[(long)u3 * 16 + sel];
            int4 w4 = *(const int4*)&yb[(long)u4 * 16 + sel];
            int4 w5 = *(const int4*)&yb[(long)u5 * 16 + sel];
            int4 w6 = *(const int4*)&yb[(long)u6 * 16 + sel];
            int4 w7 = *(const int4*)&yb[(long)u7 * 16 + sel];
            acc8(w0, a); acc8(w1, a); acc8(w2, a); acc8(w3, a);
            acc8(w4, a); acc8(w5, a); acc8(w6, a); acc8(w7, a);
        }

        __half hv[8];
#pragma unroll
        for (int j = 0; j < 8; ++j)
            hv[j] = __float2half(fmaxf(a[j] * di + b[cb * 16 + sel + j], 0.0f));
        *(int4*)&out[(long)node * 64 + cb * 16 + sel] = *(int4*)hv;
    }
}

// ---------------- gather DOUT=32: column-phased, 2 passes x 16-col plane, fp32 out ----------------

__global__ void __launch_bounds__(256) gather4h_kernel(const int* __restrict__ rowptr, const int* __restrict__ esrc,
                                                       const __half* __restrict__ ys, const float* __restrict__ dis,
                                                       const float* __restrict__ b, float* __restrict__ out, int n) {
    const int node = blockIdx.x * 128 + (threadIdx.x >> 1);
    const int sel = (threadIdx.x & 1) * 8;
    if (node >= n) return;

    const float di   = dis[node];
    const int   kbeg = rowptr[node];
    const int   end  = rowptr[node + 1];

    for (int cb = 0; cb < 2; ++cb) {
        const __half* yb = ys + (long)cb * NROW * 16;
        float a[8];
        {
            int4 sw = *(const int4*)&yb[(long)node * 16 + sel];
            __half2* h = (__half2*)&sw;
            float2 f0 = __half22float2(h[0]);
            float2 f1 = __half22float2(h[1]);
            float2 f2 = __half22float2(h[2]);
            float2 f3 = __half22float2(h[3]);
            a[0] = f0.x; a[1] = f0.y; a[2] = f1.x; a[3] = f1.y;
            a[4] = f2.x; a[5] = f2.y; a[6] = f3.x; a[7] = f3.y;
        }

        for (int k = kbeg; k < end; k += 8) {
            int u0 = (k + 0 < end) ? esrc[k + 0] : SENT;
            int u1 = (k + 1 < end) ? esrc[k + 1] : SENT;
            int u2 = (k + 2 < end) ? esrc[k + 2] : SENT;
            int u3 = (k + 3 < end) ? esrc[k + 3] : SENT;
            int u4 = (k + 4 < end) ? esrc[k + 4] : SENT;
            int u5 = (k + 5 < end) ? esrc[k + 5] : SENT;
            int u6 = (k + 6 < end) ? esrc[k + 6] : SENT;
            int u7 = (k + 7 < end) ? esrc[k + 7] : SENT;
            int4 w0 = *(const int4*)&yb[(long)u0 * 16 + sel];
            int4 w1 = *(const int4*)&yb[(long)u1 * 16 + sel];
            int4 w2 = *(const int4*)&yb[(long)u2 * 16 + sel];
            int4 w3 = *(const int4*)&yb[(long)u3 * 16 + sel];
            int4 w4 = *(const int4*)&yb[(long)u4 * 16 + sel];
            int4 w5 = *(const int4*)&yb[(long)u5 * 16 + sel];
            int4 w6 = *(const int4*)&yb[(long)u6 * 16 + sel];
            int4 w7 = *(const int4*)&yb[(long)u7 * 16 + sel];
            acc8(w0, a); acc8(w1, a); acc8(w2, a); acc8(w3, a);
            acc8(w4, a); acc8(w5, a); acc8(w6, a); acc8(w7, a);
        }

        float4 o0, o1;
        o0.x = a[0] * di + b[cb * 16 + sel + 0];
        o0.y = a[1] * di + b[cb * 16 + sel + 1];
        o0.z = a[2] * di + b[cb * 16 + sel + 2];
        o0.w = a[3] * di + b[cb * 16 + sel + 3];
        o1.x = a[4] * di + b[cb * 16 + sel + 4];
        o1.y = a[5] * di + b[cb * 16 + sel + 5];
        o1.z = a[6] * di + b[cb * 16 + sel + 6];
        o1.w = a[7] * di + b[cb * 16 + sel + 7];
        *(float4*)&out[(long)node * 32 + cb * 16 + sel] = o0;
        *(float4*)&out[(long)node * 32 + cb * 16 + sel + 4] = o1;
    }
}

// ---------------- launch ----------------

extern "C" void kernel_launch(void* const* d_in, const int* in_sizes, int n_in,
                              void* d_out, int out_size, void* d_ws, size_t ws_size,
                              hipStream_t stream) {
    const float* features = (const float*)d_in[0];
    const int*   ei       = (const int*)d_in[1];
    const float* W0 = (const float*)d_in[2];
    const float* b0 = (const float*)d_in[3];
    const float* W1 = (const float*)d_in[4];
    const float* b1 = (const float*)d_in[5];
    const float* W2 = (const float*)d_in[6];
    const float* b2 = (const float*)d_in[7];

    const int* src = ei;             // edge_index[0]
    const int* dst = ei + N_EDGES;   // edge_index[1]

    const int n = N_NODES;

    // workspace layout (int slots); H is 256*782 = 200192 ints
    int*    H      = (int*)d_ws;                       // [0, 200704)
    int*    btot   = (int*)d_ws + 200704;              // [200704, 201728)
    int*    bbase  = (int*)d_ws + 201728;              // [201728, 202752)
    int*    bptr   = (int*)d_ws + 202752;              // [202752, 204800)
    float*  dis    = (float*)d_ws + 204800;            // [204800, 335872)
    int*    rowptr = (int*)d_ws + 335872;              // [335872, 466944)   n+1 fits
    int*    tmp    = (int*)d_ws + 466944;              // E ints
    int*    esrc   = (int*)d_ws + 2066944;             // E ints
    __half* ys     = (__half*)((int*)d_ws + 3666944);  // 4 planes x 100032 x 16 halves = 3201024 ints
    __half* act    = (__half*)((int*)d_ws + 6867968);  // 100000 x 64 halves = 3200000 ints
    __half* wt0    = (__half*)((int*)d_ws + 10067968); // 8192 halves
    __half* wt1    = (__half*)((int*)d_ws + 10072064); // 4096 halves
    __half* wt2    = (__half*)((int*)d_ws + 10074112); // 2048 halves
    float*  outf   = (float*)d_out;                    // N*32 fp32

    // ---- contention-free CSR build + transposes ----
    hist_kernel<<<FBLK, 256, 0, stream>>>(dst, H);
    colscan_kernel<<<(NBK + 255) / 256, 256, 0, stream>>>(H, btot);
    bucketscan_kernel<<<1, 1024, 0, stream>>>(btot, bbase, bptr);
    binfill_kernel<<<FBLK, 256, 0, stream>>>(src, dst, H, bbase, tmp);
    bucketfin_kernel<<<NBK, 256, 0, stream>>>(tmp, bptr, esrc, rowptr, dis, n);
    transpose_all_kernel<<<57, 256, 0, stream>>>(W0, W1, W2, wt0, wt1, wt2, ys);

    // ---- layer 0: 128 -> 64, ReLU ----
    gemm_kernel<float, 128, 64><<<(n + 63) / 64, 256, 0, stream>>>(features, wt0, dis, ys, n);
    gather2h_kernel<<<(n + 127) / 128, 256, 0, stream>>>(rowptr, esrc, ys, dis, b0, act, n);

    // ---- layer 1: 64 -> 64, ReLU ----
    gemm_kernel<__half, 64, 64><<<(n + 63) / 64, 256, 0, stream>>>(act, wt1, dis, ys, n);
    gather2h_kernel<<<(n + 127) / 128, 256, 0, stream>>>(rowptr, esrc, ys, dis, b1, act, n);

    // ---- layer 2: 64 -> 32, no ReLU ----
    gemm_kernel<__half, 64, 32><<<(n + 63) / 64, 256, 0, stream>>>(act, wt2, dis, ys, n);
    gather4h_kernel<<<(n + 127) / 128, 256, 0, stream>>>(rowptr, esrc, ys, dis, b2, outf, n);
}

// Round 4
// 287.552 us; speedup vs baseline: 1.2552x; 1.2552x over previous
//
#include <hip/hip_runtime.h>
#include <hip/hip_fp16.h>

#define N_NODES 100000
#define N_EDGES 1600000
#define NPB 128                                   // nodes per dst-bucket
#define NBK ((N_NODES + NPB - 1) / NPB)           // 782 buckets
#define FBLK 256                                  // fill blocks (1 per CU)
#define EPB ((N_EDGES + FBLK - 1) / FBLK)         // 6250 edges per fill block
#define CAP 4096                                  // LDS capacity per bucket (mean 2046, sigma ~45)
#define SENT 100000                               // sentinel row (zeroed in all ys buffers)

typedef _Float16 h8 __attribute__((ext_vector_type(8)));
typedef float f4v __attribute__((ext_vector_type(4)));

// ---------------- pass 1: per-block bucket histograms + (extra block) weight transposes ----------------

__global__ void __launch_bounds__(256) hist_trans_kernel(const int* __restrict__ dst, int* __restrict__ H,
                                                         const float* __restrict__ W0, const float* __restrict__ W1,
                                                         const float* __restrict__ W2, __half* __restrict__ wt0,
                                                         __half* __restrict__ wt1, __half* __restrict__ wt2,
                                                         __half* __restrict__ ys64a, __half* __restrict__ ys64b,
                                                         __half* __restrict__ ys32) {
    if (blockIdx.x == FBLK) {
        const int t = threadIdx.x;
        for (int i = t; i < 14336; i += 256) {
            if (i < 8192)       { int k = i / 64, c = i % 64;                 wt0[c * 128 + k] = __float2half(W0[i]); }
            else if (i < 12288) { int j = i - 8192;  int k = j / 64, c = j % 64; wt1[c * 64 + k] = __float2half(W1[j]); }
            else                { int j = i - 12288; int k = j / 32, c = j % 32; wt2[c * 64 + k] = __float2half(W2[j]); }
        }
        if (t < 32) ((int*)(ys64a + (long)SENT * 64))[t] = 0;   // zero sentinel rows
        if (t < 32) ((int*)(ys64b + (long)SENT * 64))[t] = 0;
        if (t < 16) ((int*)(ys32  + (long)SENT * 32))[t] = 0;
        return;
    }
    __shared__ int h[NBK];
    for (int i = threadIdx.x; i < NBK; i += 256) h[i] = 0;
    __syncthreads();
    const int e0 = blockIdx.x * EPB;
    const int e1 = min(e0 + EPB, N_EDGES);
    for (int e = e0 + threadIdx.x; e < e1; e += 256) atomicAdd(&h[dst[e] >> 7], 1);
    __syncthreads();
    for (int i = threadIdx.x; i < NBK; i += 256) H[blockIdx.x * NBK + i] = h[i];
}

// ---------------- pass 2: fused column scan + bucket scan (single block) ----------------

__global__ void __launch_bounds__(1024) scan_kernel(int* __restrict__ H,
                                                    int* __restrict__ bbase, int* __restrict__ bptr) {
    __shared__ int sh[1024];
    const int t = threadIdx.x;
    int v = 0;
    if (t < NBK) {
        int run = 0;
        for (int k = 0; k < FBLK; ++k) {
            int idx = k * NBK + t;
            int h = H[idx];
            H[idx] = run;
            run += h;
        }
        v = run;
    }
    sh[t] = v;
    __syncthreads();
    for (int off = 1; off < 1024; off <<= 1) {
        int u = (t >= off) ? sh[t - off] : 0;
        __syncthreads();
        sh[t] += u;
        __syncthreads();
    }
    if (t < NBK) { int e = sh[t] - v; bbase[t] = e; bptr[t] = e; }
    if (t == 0) bptr[NBK] = N_EDGES;
}

// ---------------- pass 3: bin edges by bucket (LDS cursors) ----------------

__global__ void __launch_bounds__(256) binfill_kernel(const int* __restrict__ src, const int* __restrict__ dst,
                                                      const int* __restrict__ H, const int* __restrict__ bbase,
                                                      int* __restrict__ tmp) {
    __shared__ int cur[NBK];
    const int k = blockIdx.x;
    for (int i = threadIdx.x; i < NBK; i += 256) cur[i] = H[k * NBK + i] + bbase[i];
    __syncthreads();
    const int e0 = k * EPB;
    const int e1 = min(e0 + EPB, N_EDGES);
    for (int e = e0 + threadIdx.x; e < e1; e += 256) {
        int s = src[e];
        int d = dst[e];
        int pos = atomicAdd(&cur[d >> 7], 1);
        tmp[pos] = s | ((d & (NPB - 1)) << 20);
    }
}

// ---------------- pass 4: per-bucket count/scan/rowptr/dis + LDS sort -> esrc ----------------

__global__ void __launch_bounds__(256) bucketfin_kernel(const int* __restrict__ tmp, const int* __restrict__ bptr,
                                                        int* __restrict__ esrc, int* __restrict__ rowptr,
                                                        float* __restrict__ dis, int n) {
    __shared__ int buf[CAP];
    __shared__ int cnt[NPB];
    __shared__ int sc[NPB];
    __shared__ int rp[NPB];
    __shared__ int fillc[NPB];
    const int b = blockIdx.x;
    const int d0 = b * NPB;
    const int nd = min(NPB, n - d0);
    const int base = bptr[b], end = bptr[b + 1];
    const int count = end - base;
    const int tid = threadIdx.x;

    for (int i = tid; i < NPB; i += 256) { cnt[i] = 0; fillc[i] = 0; }
    __syncthreads();
    for (int e = base + tid; e < end; e += 256) atomicAdd(&cnt[tmp[e] >> 20], 1);
    __syncthreads();

    if (tid < NPB) sc[tid] = cnt[tid];
    __syncthreads();
    for (int off = 1; off < NPB; off <<= 1) {
        int v = (tid < NPB && tid >= off) ? sc[tid - off] : 0;
        __syncthreads();
        if (tid < NPB) sc[tid] += v;
        __syncthreads();
    }
    if (tid < NPB) {
        int excl = sc[tid] - cnt[tid];
        rp[tid] = excl;
        if (tid < nd) {
            rowptr[d0 + tid] = base + excl;
            dis[d0 + tid] = rsqrtf((float)cnt[tid] + 1.0f);
        }
    }
    if (b == NBK - 1 && tid == 0) rowptr[n] = N_EDGES;
    __syncthreads();

    if (count <= CAP) {
        for (int t = base + tid; t < end; t += 256) {
            int w = tmp[t];
            int ld = w >> 20;
            int pos = rp[ld] + atomicAdd(&fillc[ld], 1);
            buf[pos] = w & 0xFFFFF;
        }
        __syncthreads();
        for (int t = tid; t < count; t += 256) esrc[base + t] = buf[t];
    } else {
        for (int t = base + tid; t < end; t += 256) {
            int w = tmp[t];
            int ld = w >> 20;
            int pos = rp[ld] + atomicAdd(&fillc[ld], 1);
            esrc[base + pos] = w & 0xFFFFF;
        }
    }
}

// ---------------- MFMA GEMM (layer 0 only): ys[n,64] = fp16(dis[row] * (x[n,128] @ W)) ----------------

template <typename TIN, int DIN, int DOUT>
__global__ void __launch_bounds__(256) gemm_kernel(const TIN* __restrict__ x,
                                                   const __half* __restrict__ wt16,
                                                   const float* __restrict__ dis,
                                                   __half* __restrict__ ys, int n) {
    constexpr int WS = DIN + 8;          // half-element stride (16B-aligned, 2-way banks = free)
    constexpr int NT = DOUT / 16;
    constexpr int KC = DIN / 32;

    __shared__ _Float16 xls[64 * WS];
    __shared__ _Float16 wls[DOUT * WS];

    const int tid  = threadIdx.x;
    const int row0 = blockIdx.x * 64;

    for (int i = tid; i < DOUT * DIN / 8; i += 256) {
        int c = (i * 8) / DIN, k = (i * 8) % DIN;
        *(int4*)&wls[c * WS + k] = *(const int4*)&wt16[c * DIN + k];
    }
    if constexpr (sizeof(TIN) == 4) {            // fp32 -> fp16 convert
        for (int i = tid; i < 64 * DIN / 4; i += 256) {
            int r = (i * 4) / DIN, k = (i * 4) % DIN;
            float4 v = make_float4(0.f, 0.f, 0.f, 0.f);
            if (row0 + r < n) v = *(const float4*)&x[(long)(row0 + r) * DIN + k];
            _Float16 h[4] = {(_Float16)v.x, (_Float16)v.y, (_Float16)v.z, (_Float16)v.w};
            *(int2*)&xls[r * WS + k] = *(int2*)h;
        }
    } else {
        for (int i = tid; i < 64 * DIN / 8; i += 256) {
            int r = (i * 8) / DIN, k = (i * 8) % DIN;
            int4 v = make_int4(0, 0, 0, 0);
            if (row0 + r < n) v = *(const int4*)&x[(long)(row0 + r) * DIN + k];
            *(int4*)&xls[r * WS + k] = v;
        }
    }
    __syncthreads();

    const int wave = tid >> 6;
    const int lane = tid & 63;
    const int m16  = lane & 15;
    const int quad = lane >> 4;

    f4v acc[NT];
#pragma unroll
    for (int t = 0; t < NT; ++t) acc[t] = (f4v){0.f, 0.f, 0.f, 0.f};

    const int arow = wave * 16 + m16;
#pragma unroll
    for (int kc = 0; kc < KC; ++kc) {
        h8 a = *(const h8*)&xls[arow * WS + kc * 32 + quad * 8];
#pragma unroll
        for (int t = 0; t < NT; ++t) {
            h8 b = *(const h8*)&wls[(t * 16 + m16) * WS + kc * 32 + quad * 8];
            acc[t] = __builtin_amdgcn_mfma_f32_16x16x32_f16(a, b, acc[t], 0, 0, 0);
        }
    }

    float dsv[4];
    int   lrow[4];
#pragma unroll
    for (int reg = 0; reg < 4; ++reg) {
        lrow[reg] = wave * 16 + quad * 4 + reg;
        int grow  = row0 + lrow[reg];
        dsv[reg]  = (grow < n) ? dis[grow] : 0.f;
    }
    __syncthreads();
    _Float16* stage = xls;
#pragma unroll
    for (int t = 0; t < NT; ++t) {
#pragma unroll
        for (int reg = 0; reg < 4; ++reg)
            stage[lrow[reg] * DOUT + t * 16 + m16] = (_Float16)(acc[t][reg] * dsv[reg]);
    }
    __syncthreads();
    for (int i = tid; i < 64 * DOUT / 8; i += 256) {
        int off = i * 8;
        int r = off / DOUT;
        if (row0 + r < n)
            *(int4*)&ys[(long)row0 * DOUT + off] = *(int4*)&stage[off];
    }
}

// ---------------- gather helper: accumulate 8 halves (int4) into 8 floats ----------------

__device__ __forceinline__ void acc8(int4 w, float* a) {
    __half2* h = (__half2*)&w;
    float2 f0 = __half22float2(h[0]);
    float2 f1 = __half22float2(h[1]);
    float2 f2 = __half22float2(h[2]);
    float2 f3 = __half22float2(h[3]);
    a[0] += f0.x; a[1] += f0.y; a[2] += f1.x; a[3] += f1.y;
    a[4] += f2.x; a[5] += f2.y; a[6] += f3.x; a[7] += f3.y;
}

// ---------------- FUSED gather(64) + GEMM(64->DOUT): act tile stays in LDS ----------------
// Phase A: gather 64 nodes (2 passes x 32 nodes, 8 lanes/node x 16B) from ysin (row-major [*,64],
//          pre-scaled by dis[src]); apply dis[dst], bias, ReLU; store fp16 act tile to LDS.
// Phase B: 64xDOUTx64 MFMA GEMM on the LDS tile with staged W^T; fold dis[row]; row-major int4 store.
// act never touches global memory (saves 12.8 MB write + 12.8 MB read per layer boundary).

template <int DOUT>
__global__ void __launch_bounds__(256) fused_gg_kernel(const int* __restrict__ rowptr, const int* __restrict__ esrc,
                                                       const __half* __restrict__ ysin, const float* __restrict__ dis,
                                                       const float* __restrict__ bvec, const __half* __restrict__ wt16,
                                                       __half* __restrict__ ysout, int n) {
    constexpr int WS = 72;               // 64 + 8 halves
    constexpr int NT = DOUT / 16;

    __shared__ _Float16 xls[64 * WS];    // act tile
    __shared__ _Float16 wls[DOUT * WS];  // weights, reused as repack stage

    const int tid  = threadIdx.x;
    const int row0 = blockIdx.x * 64;

    // stage W^T fp16 (DOUT x 64), 16B chunks
    for (int i = tid; i < DOUT * 64 / 8; i += 256) {
        int c = (i * 8) / 64, k = (i * 8) % 64;
        *(int4*)&wls[c * WS + k] = *(const int4*)&wt16[c * 64 + k];
    }

    // ---- phase A: gather ----
#pragma unroll
    for (int pass = 0; pass < 2; ++pass) {
        const int lrow = pass * 32 + (tid >> 3);
        const int node = row0 + lrow;
        const int sel  = (tid & 7) * 8;
        float a[8] = {0.f, 0.f, 0.f, 0.f, 0.f, 0.f, 0.f, 0.f};
        if (node < n) {
            {
                int4 sw = *(const int4*)&ysin[(long)node * 64 + sel];   // self term (pre-scaled)
                acc8(sw, a);
            }
            const int kbeg = rowptr[node];
            const int end  = rowptr[node + 1];
            for (int k = kbeg; k < end; k += 8) {
                int u0 = (k + 0 < end) ? esrc[k + 0] : SENT;
                int u1 = (k + 1 < end) ? esrc[k + 1] : SENT;
                int u2 = (k + 2 < end) ? esrc[k + 2] : SENT;
                int u3 = (k + 3 < end) ? esrc[k + 3] : SENT;
                int u4 = (k + 4 < end) ? esrc[k + 4] : SENT;
                int u5 = (k + 5 < end) ? esrc[k + 5] : SENT;
                int u6 = (k + 6 < end) ? esrc[k + 6] : SENT;
                int u7 = (k + 7 < end) ? esrc[k + 7] : SENT;
                int4 w0 = *(const int4*)&ysin[(long)u0 * 64 + sel];
                int4 w1 = *(const int4*)&ysin[(long)u1 * 64 + sel];
                int4 w2 = *(const int4*)&ysin[(long)u2 * 64 + sel];
                int4 w3 = *(const int4*)&ysin[(long)u3 * 64 + sel];
                int4 w4 = *(const int4*)&ysin[(long)u4 * 64 + sel];
                int4 w5 = *(const int4*)&ysin[(long)u5 * 64 + sel];
                int4 w6 = *(const int4*)&ysin[(long)u6 * 64 + sel];
                int4 w7 = *(const int4*)&ysin[(long)u7 * 64 + sel];
                acc8(w0, a); acc8(w1, a); acc8(w2, a); acc8(w3, a);
                acc8(w4, a); acc8(w5, a); acc8(w6, a); acc8(w7, a);
            }
            const float di = dis[node];
#pragma unroll
            for (int j = 0; j < 8; ++j)
                a[j] = fmaxf(a[j] * di + bvec[sel + j], 0.0f);
        }
        _Float16 hv[8];
#pragma unroll
        for (int j = 0; j < 8; ++j) hv[j] = (_Float16)a[j];
        *(int4*)&xls[lrow * WS + sel] = *(int4*)hv;                // OOB rows -> zeros
    }
    __syncthreads();

    // ---- phase B: GEMM ----
    const int wave = tid >> 6;
    const int lane = tid & 63;
    const int m16  = lane & 15;
    const int quad = lane >> 4;

    f4v acc[NT];
#pragma unroll
    for (int t = 0; t < NT; ++t) acc[t] = (f4v){0.f, 0.f, 0.f, 0.f};

    const int arow = wave * 16 + m16;
#pragma unroll
    for (int kc = 0; kc < 2; ++kc) {
        h8 av = *(const h8*)&xls[arow * WS + kc * 32 + quad * 8];
#pragma unroll
        for (int t = 0; t < NT; ++t) {
            h8 bv = *(const h8*)&wls[(t * 16 + m16) * WS + kc * 32 + quad * 8];
            acc[t] = __builtin_amdgcn_mfma_f32_16x16x32_f16(av, bv, acc[t], 0, 0, 0);
        }
    }

    float dsv[4];
    int   lr[4];
#pragma unroll
    for (int reg = 0; reg < 4; ++reg) {
        lr[reg]  = wave * 16 + quad * 4 + reg;
        int grow = row0 + lr[reg];
        dsv[reg] = (grow < n) ? dis[grow] : 0.f;
    }
    __syncthreads();                                  // all waves done reading wls
    _Float16* stage = wls;                            // reuse weight LDS as repack stage
#pragma unroll
    for (int t = 0; t < NT; ++t) {
#pragma unroll
        for (int reg = 0; reg < 4; ++reg)
            stage[lr[reg] * DOUT + t * 16 + m16] = (_Float16)(acc[t][reg] * dsv[reg]);
    }
    __syncthreads();
    for (int i = tid; i < 64 * DOUT / 8; i += 256) {
        int off = i * 8;
        int r = off / DOUT;
        if (row0 + r < n)
            *(int4*)&ysout[(long)row0 * DOUT + off] = *(int4*)&stage[off];
    }
}

// ---------------- final gather DOUT=32: 16 nodes/wave, 4 lanes x 16B, sentinel-padded 8-unroll, fp32 out ----------------

__global__ void __launch_bounds__(256) gather4h_kernel(const int* __restrict__ rowptr, const int* __restrict__ esrc,
                                                       const __half* __restrict__ ys, const float* __restrict__ dis,
                                                       const float* __restrict__ b, float* __restrict__ out, int n) {
    const int node = blockIdx.x * 64 + (threadIdx.x >> 2);
    const int c = (threadIdx.x & 3) * 8;          // half index within the 32-wide row
    if (node >= n) return;

    float a[8];
    {
        int4 sw = *(const int4*)&ys[(long)node * 32 + c];
        __half2* h = (__half2*)&sw;
        float2 f0 = __half22float2(h[0]);
        float2 f1 = __half22float2(h[1]);
        float2 f2 = __half22float2(h[2]);
        float2 f3 = __half22float2(h[3]);
        a[0] = f0.x; a[1] = f0.y; a[2] = f1.x; a[3] = f1.y;
        a[4] = f2.x; a[5] = f2.y; a[6] = f3.x; a[7] = f3.y;
    }

    int k = rowptr[node];
    const int end = rowptr[node + 1];
    for (; k < end; k += 8) {
        int u0 = (k + 0 < end) ? esrc[k + 0] : SENT;
        int u1 = (k + 1 < end) ? esrc[k + 1] : SENT;
        int u2 = (k + 2 < end) ? esrc[k + 2] : SENT;
        int u3 = (k + 3 < end) ? esrc[k + 3] : SENT;
        int u4 = (k + 4 < end) ? esrc[k + 4] : SENT;
        int u5 = (k + 5 < end) ? esrc[k + 5] : SENT;
        int u6 = (k + 6 < end) ? esrc[k + 6] : SENT;
        int u7 = (k + 7 < end) ? esrc[k + 7] : SENT;
        int4 w0 = *(const int4*)&ys[(long)u0 * 32 + c];
        int4 w1 = *(const int4*)&ys[(long)u1 * 32 + c];
        int4 w2 = *(const int4*)&ys[(long)u2 * 32 + c];
        int4 w3 = *(const int4*)&ys[(long)u3 * 32 + c];
        int4 w4 = *(const int4*)&ys[(long)u4 * 32 + c];
        int4 w5 = *(const int4*)&ys[(long)u5 * 32 + c];
        int4 w6 = *(const int4*)&ys[(long)u6 * 32 + c];
        int4 w7 = *(const int4*)&ys[(long)u7 * 32 + c];
        acc8(w0, a); acc8(w1, a); acc8(w2, a); acc8(w3, a);
        acc8(w4, a); acc8(w5, a); acc8(w6, a); acc8(w7, a);
    }

    const float di = dis[node];
    float4 o0, o1;
    o0.x = a[0] * di + b[c + 0];
    o0.y = a[1] * di + b[c + 1];
    o0.z = a[2] * di + b[c + 2];
    o0.w = a[3] * di + b[c + 3];
    o1.x = a[4] * di + b[c + 4];
    o1.y = a[5] * di + b[c + 5];
    o1.z = a[6] * di + b[c + 6];
    o1.w = a[7] * di + b[c + 7];
    *(float4*)&out[(long)node * 32 + c] = o0;
    *(float4*)&out[(long)node * 32 + c + 4] = o1;
}

// ---------------- launch ----------------

extern "C" void kernel_launch(void* const* d_in, const int* in_sizes, int n_in,
                              void* d_out, int out_size, void* d_ws, size_t ws_size,
                              hipStream_t stream) {
    const float* features = (const float*)d_in[0];
    const int*   ei       = (const int*)d_in[1];
    const float* W0 = (const float*)d_in[2];
    const float* b0 = (const float*)d_in[3];
    const float* W1 = (const float*)d_in[4];
    const float* b1 = (const float*)d_in[5];
    const float* W2 = (const float*)d_in[6];
    const float* b2 = (const float*)d_in[7];

    const int* src = ei;             // edge_index[0]
    const int* dst = ei + N_EDGES;   // edge_index[1]

    const int n = N_NODES;

    // workspace layout (int slots); H is 256*782 = 200192 ints
    int*    H      = (int*)d_ws;                       // [0, 200704)
    int*    bbase  = (int*)d_ws + 200704;              // [200704, 201728)
    int*    bptr   = (int*)d_ws + 201728;              // [201728, 203776)
    float*  dis    = (float*)d_ws + 203776;            // [203776, 304128)
    int*    rowptr = (int*)d_ws + 304128;              // [304128, 404480)   n+1 fits
    int*    tmp    = (int*)d_ws + 404480;              // E ints
    int*    esrc   = (int*)d_ws + 2004480;             // E ints
    __half* ys64a  = (__half*)((int*)d_ws + 3604480);  // 100001 x 64 halves = 3200032 ints
    __half* ys64b  = (__half*)((int*)d_ws + 6804544);  // 100001 x 64 halves
    __half* ys32   = (__half*)((int*)d_ws + 10004608); // 100001 x 32 halves = 1600016 ints
    __half* wt0    = (__half*)((int*)d_ws + 11604672); // 8192 halves = 4096 ints
    __half* wt1    = (__half*)((int*)d_ws + 11608768); // 4096 halves = 2048 ints
    __half* wt2    = (__half*)((int*)d_ws + 11610816); // 2048 halves = 1024 ints
    float*  outf   = (float*)d_out;                    // N*32 fp32

    // ---- CSR build + transposes (4 kernels) ----
    hist_trans_kernel<<<FBLK + 1, 256, 0, stream>>>(dst, H, W0, W1, W2, wt0, wt1, wt2, ys64a, ys64b, ys32);
    scan_kernel<<<1, 1024, 0, stream>>>(H, bbase, bptr);
    binfill_kernel<<<FBLK, 256, 0, stream>>>(src, dst, H, bbase, tmp);
    bucketfin_kernel<<<NBK, 256, 0, stream>>>(tmp, bptr, esrc, rowptr, dis, n);

    // ---- layer 0 GEMM: features(fp32,128) -> ys64a ----
    gemm_kernel<float, 128, 64><<<(n + 63) / 64, 256, 0, stream>>>(features, wt0, dis, ys64a, n);

    // ---- fused gather(L0)+ReLU+GEMM(L1): ys64a -> ys64b ----
    fused_gg_kernel<64><<<(n + 63) / 64, 256, 0, stream>>>(rowptr, esrc, ys64a, dis, b0, wt1, ys64b, n);

    // ---- fused gather(L1)+ReLU+GEMM(L2): ys64b -> ys32 ----
    fused_gg_kernel<32><<<(n + 63) / 64, 256, 0, stream>>>(rowptr, esrc, ys64b, dis, b1, wt2, ys32, n);

    // ---- final gather(L2), no ReLU, fp32 out ----
    gather4h_kernel<<<(n + 63) / 64, 256, 0, stream>>>(rowptr, esrc, ys32, dis, b2, outf, n);
}

// Round 5
// 271.839 us; speedup vs baseline: 1.3278x; 1.0578x over previous
//
#include <hip/hip_runtime.h>
#include <hip/hip_fp16.h>

#define N_NODES 100000
#define N_EDGES 1600000
#define NPB 128                                   // nodes per dst-bucket
#define NBK ((N_NODES + NPB - 1) / NPB)           // 782 buckets
#define FBLK 256                                  // fill blocks (1 per CU); FBLK*EPB == N_EDGES exactly
#define EPB (N_EDGES / FBLK)                      // 6250 edges per fill block
#define CAP 4096                                  // LDS capacity per bucket (mean 2046, sigma ~45)
#define SENT 100000                               // sentinel row (zeroed in all ys buffers)
#define LSTR (NBK + 1)                            // stride of per-block local-offset table L

typedef _Float16 h8 __attribute__((ext_vector_type(8)));
typedef float f4v __attribute__((ext_vector_type(4)));

// ---------------- pass 1: per-block bucket histograms + local exclusive scan L + (extra block) transposes ----------------

__global__ void __launch_bounds__(256) hist_trans_kernel(const int* __restrict__ dst, int* __restrict__ H,
                                                         int* __restrict__ L,
                                                         const float* __restrict__ W0, const float* __restrict__ W1,
                                                         const float* __restrict__ W2, __half* __restrict__ wt0,
                                                         __half* __restrict__ wt1, __half* __restrict__ wt2,
                                                         __half* __restrict__ ys64a, __half* __restrict__ ys64b,
                                                         __half* __restrict__ ys32) {
    if (blockIdx.x == FBLK) {
        const int t = threadIdx.x;
        for (int i = t; i < 14336; i += 256) {
            if (i < 8192)       { int k = i / 64, c = i % 64;                 wt0[c * 128 + k] = __float2half(W0[i]); }
            else if (i < 12288) { int j = i - 8192;  int k = j / 64, c = j % 64; wt1[c * 64 + k] = __float2half(W1[j]); }
            else                { int j = i - 12288; int k = j / 32, c = j % 32; wt2[c * 64 + k] = __float2half(W2[j]); }
        }
        if (t < 32) ((int*)(ys64a + (long)SENT * 64))[t] = 0;   // zero sentinel rows
        if (t < 32) ((int*)(ys64b + (long)SENT * 64))[t] = 0;
        if (t < 16) ((int*)(ys32  + (long)SENT * 32))[t] = 0;
        return;
    }
    __shared__ int h[NBK];
    __shared__ int sc[256];
    const int k = blockIdx.x;
    const int tid = threadIdx.x;
    for (int i = tid; i < NBK; i += 256) h[i] = 0;
    __syncthreads();
    const int e0 = k * EPB;
    for (int e = e0 + tid; e < e0 + EPB; e += 256) atomicAdd(&h[dst[e] >> 7], 1);
    __syncthreads();
    for (int i = tid; i < NBK; i += 256) H[k * NBK + i] = h[i];

    // exclusive scan of h over the 782 buckets -> L[k][*] (block-local offsets)
    int run = 0;
    for (int c0 = 0; c0 < NBK; c0 += 256) {
        int idx = c0 + tid;
        int v = (idx < NBK) ? h[idx] : 0;
        sc[tid] = v;
        __syncthreads();
        for (int off = 1; off < 256; off <<= 1) {
            int u = (tid >= off) ? sc[tid - off] : 0;
            __syncthreads();
            sc[tid] += u;
            __syncthreads();
        }
        if (idx < NBK) L[k * LSTR + idx] = run + sc[tid] - v;
        int chunktot = sc[255];
        __syncthreads();
        run += chunktot;
    }
    if (tid == 0) L[k * LSTR + NBK] = run;      // == EPB
}

// ---------------- pass 2a: bucket totals (parallel reduction, one block per bucket) ----------------

__global__ void __launch_bounds__(256) btot_kernel(const int* __restrict__ H, int* __restrict__ btot) {
    __shared__ int s[256];
    const int t = blockIdx.x;
    s[threadIdx.x] = H[threadIdx.x * NBK + t];
    __syncthreads();
    for (int off = 128; off; off >>= 1) {
        if (threadIdx.x < off) s[threadIdx.x] += s[threadIdx.x + off];
        __syncthreads();
    }
    if (threadIdx.x == 0) btot[t] = s[0];
}

// ---------------- pass 2b: scan bucket totals -> bptr ----------------

__global__ void __launch_bounds__(1024) bptr_kernel(const int* __restrict__ btot, int* __restrict__ bptr) {
    __shared__ int sh[1024];
    const int t = threadIdx.x;
    int v = (t < NBK) ? btot[t] : 0;
    sh[t] = v;
    __syncthreads();
    for (int off = 1; off < 1024; off <<= 1) {
        int u = (t >= off) ? sh[t - off] : 0;
        __syncthreads();
        sh[t] += u;
        __syncthreads();
    }
    if (t < NBK) bptr[t] = sh[t] - v;
    if (t == 0) bptr[NBK] = N_EDGES;
}

// ---------------- pass 3: per-block LDS counting sort -> block-major tmp (fully coalesced writes) ----------------

__global__ void __launch_bounds__(256) binfill_kernel(const int* __restrict__ src, const int* __restrict__ dst,
                                                      const int* __restrict__ L, int* __restrict__ tmp) {
    __shared__ int cur[NBK];
    __shared__ int sbuf[EPB];
    const int k = blockIdx.x;
    const int tid = threadIdx.x;
    for (int i = tid; i < NBK; i += 256) cur[i] = L[k * LSTR + i];
    __syncthreads();
    const int e0 = k * EPB;
    for (int e = e0 + tid; e < e0 + EPB; e += 256) {
        int s = src[e];
        int d = dst[e];
        int pos = atomicAdd(&cur[d >> 7], 1);
        sbuf[pos] = s | ((d & (NPB - 1)) << 20);
    }
    __syncthreads();
    for (int i = tid; i < EPB; i += 256) tmp[e0 + i] = sbuf[i];
}

// ---------------- pass 4: segment-gather via L + per-bucket count/scan/rowptr/dis + LDS sort -> esrc ----------------

__global__ void __launch_bounds__(256) bucketfin_kernel(const int* __restrict__ tmp, const int* __restrict__ L,
                                                        const int* __restrict__ bptr,
                                                        int* __restrict__ esrc, int* __restrict__ rowptr,
                                                        float* __restrict__ dis, int n) {
    __shared__ int buf[CAP];
    __shared__ int buf2[CAP];
    __shared__ int cnt[NPB];
    __shared__ int sc[NPB];
    __shared__ int rp[NPB];
    __shared__ int fillc[NPB];
    __shared__ int segb[256];
    const int b = blockIdx.x;
    const int tid = threadIdx.x;
    const int d0 = b * NPB;
    const int nd = min(NPB, n - d0);
    const int base = bptr[b];

    // my segment of bucket b inside fill-block tid's region
    const int lb = L[tid * LSTR + b];
    const int le = L[tid * LSTR + b + 1];
    const int c  = le - lb;

    // exclusive scan of segment sizes over the 256 fill blocks
    segb[tid] = c;
    __syncthreads();
    for (int off = 1; off < 256; off <<= 1) {
        int u = (tid >= off) ? segb[tid - off] : 0;
        __syncthreads();
        segb[tid] += u;
        __syncthreads();
    }
    const int my0   = segb[tid] - c;
    const int count = segb[255];

    for (int i = tid; i < NPB; i += 256) { cnt[i] = 0; fillc[i] = 0; }
    __syncthreads();

    const int* seg = tmp + tid * EPB + lb;
    if (count <= CAP) {
        for (int j = 0; j < c; ++j) buf[my0 + j] = seg[j];
        __syncthreads();
        for (int e = tid; e < count; e += 256) atomicAdd(&cnt[buf[e] >> 20], 1);
        __syncthreads();
    } else {                                   // statistically unreachable (count ~2046, CAP 4096)
        for (int j = 0; j < c; ++j) atomicAdd(&cnt[seg[j] >> 20], 1);
        __syncthreads();
    }

    if (tid < NPB) sc[tid] = cnt[tid];
    __syncthreads();
    for (int off = 1; off < NPB; off <<= 1) {
        int v = (tid < NPB && tid >= off) ? sc[tid - off] : 0;
        __syncthreads();
        if (tid < NPB) sc[tid] += v;
        __syncthreads();
    }
    if (tid < NPB) {
        int excl = sc[tid] - cnt[tid];
        rp[tid] = excl;
        if (tid < nd) {
            rowptr[d0 + tid] = base + excl;
            dis[d0 + tid] = rsqrtf((float)cnt[tid] + 1.0f);
        }
    }
    if (b == NBK - 1 && tid == 0) rowptr[n] = N_EDGES;
    __syncthreads();

    if (count <= CAP) {
        for (int e = tid; e < count; e += 256) {
            int w = buf[e];
            int ld = w >> 20;
            int pos = rp[ld] + atomicAdd(&fillc[ld], 1);
            buf2[pos] = w & 0xFFFFF;
        }
        __syncthreads();
        for (int e = tid; e < count; e += 256) esrc[base + e] = buf2[e];
    } else {
        for (int j = 0; j < c; ++j) {
            int w = seg[j];
            int ld = w >> 20;
            int pos = rp[ld] + atomicAdd(&fillc[ld], 1);
            esrc[base + pos] = w & 0xFFFFF;
        }
    }
}

// ---------------- MFMA GEMM (layer 0 only): ys[n,64] = fp16(dis[row] * (x[n,128] @ W)) ----------------

template <typename TIN, int DIN, int DOUT>
__global__ void __launch_bounds__(256) gemm_kernel(const TIN* __restrict__ x,
                                                   const __half* __restrict__ wt16,
                                                   const float* __restrict__ dis,
                                                   __half* __restrict__ ys, int n) {
    constexpr int WS = DIN + 8;          // half-element stride (16B-aligned, 2-way banks = free)
    constexpr int NT = DOUT / 16;
    constexpr int KC = DIN / 32;

    __shared__ _Float16 xls[64 * WS];
    __shared__ _Float16 wls[DOUT * WS];

    const int tid  = threadIdx.x;
    const int row0 = blockIdx.x * 64;

    for (int i = tid; i < DOUT * DIN / 8; i += 256) {
        int c = (i * 8) / DIN, k = (i * 8) % DIN;
        *(int4*)&wls[c * WS + k] = *(const int4*)&wt16[c * DIN + k];
    }
    if constexpr (sizeof(TIN) == 4) {            // fp32 -> fp16 convert
        for (int i = tid; i < 64 * DIN / 4; i += 256) {
            int r = (i * 4) / DIN, k = (i * 4) % DIN;
            float4 v = make_float4(0.f, 0.f, 0.f, 0.f);
            if (row0 + r < n) v = *(const float4*)&x[(long)(row0 + r) * DIN + k];
            _Float16 h[4] = {(_Float16)v.x, (_Float16)v.y, (_Float16)v.z, (_Float16)v.w};
            *(int2*)&xls[r * WS + k] = *(int2*)h;
        }
    } else {
        for (int i = tid; i < 64 * DIN / 8; i += 256) {
            int r = (i * 8) / DIN, k = (i * 8) % DIN;
            int4 v = make_int4(0, 0, 0, 0);
            if (row0 + r < n) v = *(const int4*)&x[(long)(row0 + r) * DIN + k];
            *(int4*)&xls[r * WS + k] = v;
        }
    }
    __syncthreads();

    const int wave = tid >> 6;
    const int lane = tid & 63;
    const int m16  = lane & 15;
    const int quad = lane >> 4;

    f4v acc[NT];
#pragma unroll
    for (int t = 0; t < NT; ++t) acc[t] = (f4v){0.f, 0.f, 0.f, 0.f};

    const int arow = wave * 16 + m16;
#pragma unroll
    for (int kc = 0; kc < KC; ++kc) {
        h8 a = *(const h8*)&xls[arow * WS + kc * 32 + quad * 8];
#pragma unroll
        for (int t = 0; t < NT; ++t) {
            h8 b = *(const h8*)&wls[(t * 16 + m16) * WS + kc * 32 + quad * 8];
            acc[t] = __builtin_amdgcn_mfma_f32_16x16x32_f16(a, b, acc[t], 0, 0, 0);
        }
    }

    float dsv[4];
    int   lrow[4];
#pragma unroll
    for (int reg = 0; reg < 4; ++reg) {
        lrow[reg] = wave * 16 + quad * 4 + reg;
        int grow  = row0 + lrow[reg];
        dsv[reg]  = (grow < n) ? dis[grow] : 0.f;
    }
    __syncthreads();
    _Float16* stage = xls;
#pragma unroll
    for (int t = 0; t < NT; ++t) {
#pragma unroll
        for (int reg = 0; reg < 4; ++reg)
            stage[lrow[reg] * DOUT + t * 16 + m16] = (_Float16)(acc[t][reg] * dsv[reg]);
    }
    __syncthreads();
    for (int i = tid; i < 64 * DOUT / 8; i += 256) {
        int off = i * 8;
        int r = off / DOUT;
        if (row0 + r < n)
            *(int4*)&ys[(long)row0 * DOUT + off] = *(int4*)&stage[off];
    }
}

// ---------------- gather helper: accumulate 8 halves (int4) into 8 floats ----------------

__device__ __forceinline__ void acc8(int4 w, float* a) {
    __half2* h = (__half2*)&w;
    float2 f0 = __half22float2(h[0]);
    float2 f1 = __half22float2(h[1]);
    float2 f2 = __half22float2(h[2]);
    float2 f3 = __half22float2(h[3]);
    a[0] += f0.x; a[1] += f0.y; a[2] += f1.x; a[3] += f1.y;
    a[4] += f2.x; a[5] += f2.y; a[6] += f3.x; a[7] += f3.y;
}

// ---------------- FUSED gather(64) + GEMM(64->DOUT): act tile stays in LDS ----------------

template <int DOUT>
__global__ void __launch_bounds__(256) fused_gg_kernel(const int* __restrict__ rowptr, const int* __restrict__ esrc,
                                                       const __half* __restrict__ ysin, const float* __restrict__ dis,
                                                       const float* __restrict__ bvec, const __half* __restrict__ wt16,
                                                       __half* __restrict__ ysout, int n) {
    constexpr int WS = 72;               // 64 + 8 halves
    constexpr int NT = DOUT / 16;

    __shared__ _Float16 xls[64 * WS];    // act tile
    __shared__ _Float16 wls[DOUT * WS];  // weights, reused as repack stage

    const int tid  = threadIdx.x;
    const int row0 = blockIdx.x * 64;

    for (int i = tid; i < DOUT * 64 / 8; i += 256) {
        int c = (i * 8) / 64, k = (i * 8) % 64;
        *(int4*)&wls[c * WS + k] = *(const int4*)&wt16[c * 64 + k];
    }

    // ---- phase A: gather ----
#pragma unroll
    for (int pass = 0; pass < 2; ++pass) {
        const int lrow = pass * 32 + (tid >> 3);
        const int node = row0 + lrow;
        const int sel  = (tid & 7) * 8;
        float a[8] = {0.f, 0.f, 0.f, 0.f, 0.f, 0.f, 0.f, 0.f};
        if (node < n) {
            {
                int4 sw = *(const int4*)&ysin[(long)node * 64 + sel];   // self term (pre-scaled)
                acc8(sw, a);
            }
            const int kbeg = rowptr[node];
            const int end  = rowptr[node + 1];
            for (int k = kbeg; k < end; k += 8) {
                int u0 = (k + 0 < end) ? esrc[k + 0] : SENT;
                int u1 = (k + 1 < end) ? esrc[k + 1] : SENT;
                int u2 = (k + 2 < end) ? esrc[k + 2] : SENT;
                int u3 = (k + 3 < end) ? esrc[k + 3] : SENT;
                int u4 = (k + 4 < end) ? esrc[k + 4] : SENT;
                int u5 = (k + 5 < end) ? esrc[k + 5] : SENT;
                int u6 = (k + 6 < end) ? esrc[k + 6] : SENT;
                int u7 = (k + 7 < end) ? esrc[k + 7] : SENT;
                int4 w0 = *(const int4*)&ysin[(long)u0 * 64 + sel];
                int4 w1 = *(const int4*)&ysin[(long)u1 * 64 + sel];
                int4 w2 = *(const int4*)&ysin[(long)u2 * 64 + sel];
                int4 w3 = *(const int4*)&ysin[(long)u3 * 64 + sel];
                int4 w4 = *(const int4*)&ysin[(long)u4 * 64 + sel];
                int4 w5 = *(const int4*)&ysin[(long)u5 * 64 + sel];
                int4 w6 = *(const int4*)&ysin[(long)u6 * 64 + sel];
                int4 w7 = *(const int4*)&ysin[(long)u7 * 64 + sel];
                acc8(w0, a); acc8(w1, a); acc8(w2, a); acc8(w3, a);
                acc8(w4, a); acc8(w5, a); acc8(w6, a); acc8(w7, a);
            }
            const float di = dis[node];
#pragma unroll
            for (int j = 0; j < 8; ++j)
                a[j] = fmaxf(a[j] * di + bvec[sel + j], 0.0f);
        }
        _Float16 hv[8];
#pragma unroll
        for (int j = 0; j < 8; ++j) hv[j] = (_Float16)a[j];
        *(int4*)&xls[lrow * WS + sel] = *(int4*)hv;                // OOB rows -> zeros
    }
    __syncthreads();

    // ---- phase B: GEMM ----
    const int wave = tid >> 6;
    const int lane = tid & 63;
    const int m16  = lane & 15;
    const int quad = lane >> 4;

    f4v acc[NT];
#pragma unroll
    for (int t = 0; t < NT; ++t) acc[t] = (f4v){0.f, 0.f, 0.f, 0.f};

    const int arow = wave * 16 + m16;
#pragma unroll
    for (int kc = 0; kc < 2; ++kc) {
        h8 av = *(const h8*)&xls[arow * WS + kc * 32 + quad * 8];
#pragma unroll
        for (int t = 0; t < NT; ++t) {
            h8 bv = *(const h8*)&wls[(t * 16 + m16) * WS + kc * 32 + quad * 8];
            acc[t] = __builtin_amdgcn_mfma_f32_16x16x32_f16(av, bv, acc[t], 0, 0, 0);
        }
    }

    float dsv[4];
    int   lr[4];
#pragma unroll
    for (int reg = 0; reg < 4; ++reg) {
        lr[reg]  = wave * 16 + quad * 4 + reg;
        int grow = row0 + lr[reg];
        dsv[reg] = (grow < n) ? dis[grow] : 0.f;
    }
    __syncthreads();                                  // all waves done reading wls
    _Float16* stage = wls;                            // reuse weight LDS as repack stage
#pragma unroll
    for (int t = 0; t < NT; ++t) {
#pragma unroll
        for (int reg = 0; reg < 4; ++reg)
            stage[lr[reg] * DOUT + t * 16 + m16] = (_Float16)(acc[t][reg] * dsv[reg]);
    }
    __syncthreads();
    for (int i = tid; i < 64 * DOUT / 8; i += 256) {
        int off = i * 8;
        int r = off / DOUT;
        if (row0 + r < n)
            *(int4*)&ysout[(long)row0 * DOUT + off] = *(int4*)&stage[off];
    }
}

// ---------------- final gather DOUT=32: 16 nodes/wave, 4 lanes x 16B, sentinel-padded 8-unroll, fp32 out ----------------

__global__ void __launch_bounds__(256) gather4h_kernel(const int* __restrict__ rowptr, const int* __restrict__ esrc,
                                                       const __half* __restrict__ ys, const float* __restrict__ dis,
                                                       const float* __restrict__ b, float* __restrict__ out, int n) {
    const int node = blockIdx.x * 64 + (threadIdx.x >> 2);
    const int c = (threadIdx.x & 3) * 8;          // half index within the 32-wide row
    if (node >= n) return;

    float a[8];
    {
        int4 sw = *(const int4*)&ys[(long)node * 32 + c];
        __half2* h = (__half2*)&sw;
        float2 f0 = __half22float2(h[0]);
        float2 f1 = __half22float2(h[1]);
        float2 f2 = __half22float2(h[2]);
        float2 f3 = __half22float2(h[3]);
        a[0] = f0.x; a[1] = f0.y; a[2] = f1.x; a[3] = f1.y;
        a[4] = f2.x; a[5] = f2.y; a[6] = f3.x; a[7] = f3.y;
    }

    int k = rowptr[node];
    const int end = rowptr[node + 1];
    for (; k < end; k += 8) {
        int u0 = (k + 0 < end) ? esrc[k + 0] : SENT;
        int u1 = (k + 1 < end) ? esrc[k + 1] : SENT;
        int u2 = (k + 2 < end) ? esrc[k + 2] : SENT;
        int u3 = (k + 3 < end) ? esrc[k + 3] : SENT;
        int u4 = (k + 4 < end) ? esrc[k + 4] : SENT;
        int u5 = (k + 5 < end) ? esrc[k + 5] : SENT;
        int u6 = (k + 6 < end) ? esrc[k + 6] : SENT;
        int u7 = (k + 7 < end) ? esrc[k + 7] : SENT;
        int4 w0 = *(const int4*)&ys[(long)u0 * 32 + c];
        int4 w1 = *(const int4*)&ys[(long)u1 * 32 + c];
        int4 w2 = *(const int4*)&ys[(long)u2 * 32 + c];
        int4 w3 = *(const int4*)&ys[(long)u3 * 32 + c];
        int4 w4 = *(const int4*)&ys[(long)u4 * 32 + c];
        int4 w5 = *(const int4*)&ys[(long)u5 * 32 + c];
        int4 w6 = *(const int4*)&ys[(long)u6 * 32 + c];
        int4 w7 = *(const int4*)&ys[(long)u7 * 32 + c];
        acc8(w0, a); acc8(w1, a); acc8(w2, a); acc8(w3, a);
        acc8(w4, a); acc8(w5, a); acc8(w6, a); acc8(w7, a);
    }

    const float di = dis[node];
    float4 o0, o1;
    o0.x = a[0] * di + b[c + 0];
    o0.y = a[1] * di + b[c + 1];
    o0.z = a[2] * di + b[c + 2];
    o0.w = a[3] * di + b[c + 3];
    o1.x = a[4] * di + b[c + 4];
    o1.y = a[5] * di + b[c + 5];
    o1.z = a[6] * di + b[c + 6];
    o1.w = a[7] * di + b[c + 7];
    *(float4*)&out[(long)node * 32 + c] = o0;
    *(float4*)&out[(long)node * 32 + c + 4] = o1;
}

// ---------------- launch ----------------

extern "C" void kernel_launch(void* const* d_in, const int* in_sizes, int n_in,
                              void* d_out, int out_size, void* d_ws, size_t ws_size,
                              hipStream_t stream) {
    const float* features = (const float*)d_in[0];
    const int*   ei       = (const int*)d_in[1];
    const float* W0 = (const float*)d_in[2];
    const float* b0 = (const float*)d_in[3];
    const float* W1 = (const float*)d_in[4];
    const float* b1 = (const float*)d_in[5];
    const float* W2 = (const float*)d_in[6];
    const float* b2 = (const float*)d_in[7];

    const int* src = ei;             // edge_index[0]
    const int* dst = ei + N_EDGES;   // edge_index[1]

    const int n = N_NODES;

    // workspace layout (int slots)
    int*    H      = (int*)d_ws;                       // 256*782   -> [0, 200704)
    int*    L      = (int*)d_ws + 200704;              // 256*783   -> [200704, 401408)
    int*    btot   = (int*)d_ws + 401408;              // [401408, 402432)
    int*    bptr   = (int*)d_ws + 402432;              // [402432, 404480)
    float*  dis    = (float*)d_ws + 404480;            // [404480, 504832)
    int*    rowptr = (int*)d_ws + 504832;              // [504832, 605184)   n+1 fits
    int*    tmp    = (int*)d_ws + 605184;              // E ints (block-major)
    int*    esrc   = (int*)d_ws + 2205184;             // E ints
    __half* ys64a  = (__half*)((int*)d_ws + 3805184);  // 100001 x 64 halves = 3200032 ints
    __half* ys64b  = (__half*)((int*)d_ws + 7005216);  // 100001 x 64 halves
    __half* ys32   = (__half*)((int*)d_ws + 10205248); // 100001 x 32 halves = 1600016 ints
    __half* wt0    = (__half*)((int*)d_ws + 11805264); // 8192 halves = 4096 ints
    __half* wt1    = (__half*)((int*)d_ws + 11809360); // 4096 halves = 2048 ints
    __half* wt2    = (__half*)((int*)d_ws + 11811408); // 2048 halves = 1024 ints
    float*  outf   = (float*)d_out;                    // N*32 fp32

    // ---- CSR build + transposes (5 kernels) ----
    hist_trans_kernel<<<FBLK + 1, 256, 0, stream>>>(dst, H, L, W0, W1, W2, wt0, wt1, wt2, ys64a, ys64b, ys32);
    btot_kernel<<<NBK, 256, 0, stream>>>(H, btot);
    bptr_kernel<<<1, 1024, 0, stream>>>(btot, bptr);
    binfill_kernel<<<FBLK, 256, 0, stream>>>(src, dst, L, tmp);
    bucketfin_kernel<<<NBK, 256, 0, stream>>>(tmp, L, bptr, esrc, rowptr, dis, n);

    // ---- layer 0 GEMM: features(fp32,128) -> ys64a ----
    gemm_kernel<float, 128, 64><<<(n + 63) / 64, 256, 0, stream>>>(features, wt0, dis, ys64a, n);

    // ---- fused gather(L0)+ReLU+GEMM(L1): ys64a -> ys64b ----
    fused_gg_kernel<64><<<(n + 63) / 64, 256, 0, stream>>>(rowptr, esrc, ys64a, dis, b0, wt1, ys64b, n);

    // ---- fused gather(L1)+ReLU+GEMM(L2): ys64b -> ys32 ----
    fused_gg_kernel<32><<<(n + 63) / 64, 256, 0, stream>>>(rowptr, esrc, ys64b, dis, b1, wt2, ys32, n);

    // ---- final gather(L2), no ReLU, fp32 out ----
    gather4h_kernel<<<(n + 63) / 64, 256, 0, stream>>>(rowptr, esrc, ys32, dis, b2, outf, n);
}